// Round 14
// baseline (247.594 us; speedup 1.0000x reference)
//
#include <hip/hip_runtime.h>
#include <math.h>

typedef _Float16 f16;
typedef f16 f16x8 __attribute__((ext_vector_type(8)));
typedef f16 f16x2 __attribute__((ext_vector_type(2)));
typedef float f32x4 __attribute__((ext_vector_type(4)));

constexpr int NN = 10000;      // nodes
constexpr int NE = 160000;     // edges (before self-loops)
constexpr int MPAD = 10112;    // 79 * 128, row padding for 128-tiles
constexpr int D_IN = 128, D_H1 = 512, D_H2 = 1024, D_H3 = 512, D_OUT = 32;

// ---------------------------------------------------------------------------
// Kernel 1: all one-shot prep — zero degi, convert weights (transposed fp16,
// K-contiguous), convert x to fp16. No inter-dependencies.
// ---------------------------------------------------------------------------
__global__ void prep_all(const float* __restrict__ W1, const float* __restrict__ W2,
                         const float* __restrict__ W3, const float* __restrict__ W4,
                         const float* __restrict__ x,
                         f16* __restrict__ Wt1, f16* __restrict__ Wt2,
                         f16* __restrict__ Wt3, f16* __restrict__ Wt4,
                         f16* __restrict__ xh, int* __restrict__ degi) {
    int idx = blockIdx.x * blockDim.x + threadIdx.x;
    if (idx < 512 * 128) {               // Wt1 [512][128] <- W1 [128][512]
        int n = idx >> 7, k = idx & 127;
        Wt1[idx] = (f16)W1[k * 512 + n];
        return;
    }
    idx -= 512 * 128;
    if (idx < 1024 * 512) {              // Wt2 [1024][512] <- W2 [512][1024]
        int n = idx >> 9, k = idx & 511;
        Wt2[idx] = (f16)W2[k * 1024 + n];
        return;
    }
    idx -= 1024 * 512;
    if (idx < 512 * 1024) {              // Wt3 [512][1024] <- W3 [1024][512]
        int n = idx >> 10, k = idx & 1023;
        Wt3[idx] = (f16)W3[k * 512 + n];
        return;
    }
    idx -= 512 * 1024;
    if (idx < 128 * 512) {               // Wt4 [128][512] <- W4 [512][32], zero-padded
        int n = idx >> 9, k = idx & 511;
        Wt4[idx] = (n < 32) ? (f16)W4[k * 32 + n] : (f16)0.f;
        return;
    }
    idx -= 128 * 512;
    if (idx < NN * D_IN) {               // xh <- x (fp32 -> fp16)
        xh[idx] = (f16)x[idx];
        return;
    }
    idx -= NN * D_IN;
    if (idx < NN) degi[idx] = 0;
}

// Count in-degrees straight from edge_index (layout detected per-wave).
// int64 layout => odd 32-bit words of the src row all zero (ids<10000);
// int32 layout: P(64 consecutive odd words all zero) ~ (1e-4)^64 ~ 0.
__global__ void count_deg(const int* __restrict__ e, int* __restrict__ degi) {
    int i = blockIdx.x * blockDim.x + threadIdx.x;
    bool nz = (i < NE) && (e[2 * i + 1] != 0);
    bool is32 = __any(nz);               // wave-uniform layout verdict
    if (i >= NE) return;
    int d = is32 ? e[NE + i] : e[2 * NE + 2 * i];
    atomicAdd(&degi[d], 1);
}

// Single-block scan: int4-vectorized (4 elems/thread, 3 outer iters),
// degi -> rowptr (exclusive) + fill copy + dinv.
__global__ __launch_bounds__(1024) void scan_rowptr(
    const int* __restrict__ degi, int* __restrict__ rowptr,
    int* __restrict__ fill, float* __restrict__ dinv) {
    __shared__ int wsum[16];
    __shared__ int carry_s;
    int tid = threadIdx.x;
    int lane = tid & 63, wid = tid >> 6;
    if (tid == 0) carry_s = 0;
    for (int base = 0; base < NN; base += 4096) {
        int i4 = base + tid * 4;
        int4 v = {0, 0, 0, 0};
        if (i4 + 3 < NN) {
            v = *reinterpret_cast<const int4*>(degi + i4);
        } else {
            if (i4 + 0 < NN) v.x = degi[i4 + 0];
            if (i4 + 1 < NN) v.y = degi[i4 + 1];
            if (i4 + 2 < NN) v.z = degi[i4 + 2];
            if (i4 + 3 < NN) v.w = degi[i4 + 3];
        }
        if (i4 + 0 < NN) dinv[i4 + 0] = rsqrtf((float)(v.x + 1));  // +1 self-loop
        if (i4 + 1 < NN) dinv[i4 + 1] = rsqrtf((float)(v.y + 1));
        if (i4 + 2 < NN) dinv[i4 + 2] = rsqrtf((float)(v.z + 1));
        if (i4 + 3 < NN) dinv[i4 + 3] = rsqrtf((float)(v.w + 1));
        // serial inclusive scan of the 4 local elements
        int s1 = v.x, s2 = s1 + v.y, s3 = s2 + v.z, s4 = s3 + v.w;
        // wave inclusive scan of thread totals
        int xs = s4;
#pragma unroll
        for (int off = 1; off < 64; off <<= 1) {
            int t = __shfl_up(xs, off, 64);
            if (lane >= off) xs += t;
        }
        if (lane == 63) wsum[wid] = xs;
        __syncthreads();                       // B1 (also covers carry_s update)
        if (tid < 16) {
            int y = wsum[tid];
#pragma unroll
            for (int off = 1; off < 16; off <<= 1) {
                int t = __shfl_up(y, off, 16);
                if (tid >= off) y += t;
            }
            wsum[tid] = y;
        }
        __syncthreads();                       // B2
        int woff = wid ? wsum[wid - 1] : 0;
        int excl = (xs - s4) + woff + carry_s; // exclusive prefix of elem 0
        int4 r; r.x = excl; r.y = excl + s1; r.z = excl + s2; r.w = excl + s3;
        if (i4 + 3 < NN) {
            *reinterpret_cast<int4*>(rowptr + i4) = r;
            *reinterpret_cast<int4*>(fill + i4)   = r;
        } else {
            if (i4 + 0 < NN) { rowptr[i4 + 0] = r.x; fill[i4 + 0] = r.x; }
            if (i4 + 1 < NN) { rowptr[i4 + 1] = r.y; fill[i4 + 1] = r.y; }
            if (i4 + 2 < NN) { rowptr[i4 + 2] = r.z; fill[i4 + 2] = r.z; }
            if (i4 + 3 < NN) { rowptr[i4 + 3] = r.w; fill[i4 + 3] = r.w; }
        }
        __syncthreads();                       // B3: all carry_s reads done
        if (tid == 1023) carry_s = excl + s4;
    }
    if (tid == 1023) rowptr[NN] = carry_s;
}

// CSR scatter, packing {src, dinv[src]} per edge so the agg inner loop has a
// single random hop (the gather) and one sequential 8B load.
__global__ void scatter_edges(const int* __restrict__ e, const float* __restrict__ dinv,
                              int* __restrict__ fill, int2* __restrict__ colw) {
    int i = blockIdx.x * blockDim.x + threadIdx.x;
    bool nz = (i < NE) && (e[2 * i + 1] != 0);
    bool is32 = __any(nz);               // wave-uniform layout verdict
    if (i >= NE) return;
    int s, d;
    if (is32) { s = e[i];     d = e[NE + i]; }
    else      { s = e[2 * i]; d = e[2 * NE + 2 * i]; }
    int p = atomicAdd(&fill[d], 1);
    colw[p] = make_int2(s, __float_as_int(dinv[s]));
}

// ---------------------------------------------------------------------------
// Pull aggregation (fp16 in/out): 256-thread blocks, 4 nodes/block (1 wave ea).
// out[n,:] = dinv[n]^2*in[n,:] + sum_e dinv[n]*dinv[src]*in[src,:]
// MODE 0: plain   MODE 1: +bias, relu.  VEC in {2,8}, D = 64*VEC.
// Edge loop: 1 sequential int2 load + 1 gather per edge, unrolled 8-deep.
// ---------------------------------------------------------------------------
template <int VEC>
__device__ __forceinline__ void acc_row(const f16* p, float w, float (&a)[VEC]) {
    if constexpr (VEC == 8) {
        f16x8 t = *reinterpret_cast<const f16x8*>(p);
#pragma unroll
        for (int j = 0; j < 8; ++j) a[j] = fmaf(w, (float)t[j], a[j]);
    } else {
        f16x2 t = *reinterpret_cast<const f16x2*>(p);
        a[0] = fmaf(w, (float)t[0], a[0]);
        a[1] = fmaf(w, (float)t[1], a[1]);
    }
}

template <int VEC, int MODE>
__global__ __launch_bounds__(256) void agg_kernel(
    const f16* __restrict__ in, f16* __restrict__ out,
    const int* __restrict__ rowptr, const int2* __restrict__ colw,
    const float* __restrict__ dinv, const float* __restrict__ bias) {
    const int D = 64 * VEC;
    int n = blockIdx.x * 4 + (threadIdx.x >> 6);
    if (n >= NN) return;
    int lane = threadIdx.x & 63;
    int d0 = lane * VEC;
    float di = dinv[n];
    float acc[VEC];
#pragma unroll
    for (int v = 0; v < VEC; ++v) acc[v] = 0.f;
    acc_row<VEC>(in + (size_t)n * D + d0, di * di, acc);
    int e0 = rowptr[n], e1 = rowptr[n + 1];
#pragma unroll 8
    for (int e = e0; e < e1; ++e) {
        int2 cw = colw[e];
        acc_row<VEC>(in + (size_t)cw.x * D + d0, di * __int_as_float(cw.y), acc);
    }
    f16 o[VEC];
#pragma unroll
    for (int v = 0; v < VEC; ++v) {
        float xv = acc[v];
        if (MODE >= 1) xv += bias[d0 + v];
        if (MODE == 1) xv = fmaxf(xv, 0.f);
        o[v] = (f16)xv;
    }
    if constexpr (VEC == 8)
        *reinterpret_cast<f16x8*>(out + (size_t)n * D + d0) = *reinterpret_cast<f16x8*>(o);
    else
        *reinterpret_cast<f16x2*>(out + (size_t)n * D + d0) = *reinterpret_cast<f16x2*>(o);
}

// ---------------------------------------------------------------------------
// fp16 MFMA GEMM v2: C[M,N] = A[M,K] @ Bt[N,K]^T, fp32 accumulate, fp16 out.
// 128x128 tile, BK=64, double-buffered LDS, 2-phase prefetch pipeline
// (stage t+1 -> compute t -> one barrier/iter). 256 threads = 4 waves (2x2),
// 64x64/wave, mfma_f32_16x16x32_f16 4x4 frags, 2 k-steps per tile.
// M%128==0, N%128==0, K%64==0.
// LDS linear dest (global_load_lds); 16B-slot XOR swizzle (8 slots/row):
// source slot g = lin ^ (row&7), ds_read slot (kk*4+kg) ^ (row&7) — same
// involution both sides (rule 21); 2-way residual bank aliasing = free.
// XCD-bijective block swizzle (m204). MODE 0: plain  MODE 1: +bias, relu.
// ---------------------------------------------------------------------------
__device__ __forceinline__ void gload_lds16(const void* g, void* lds) {
    __builtin_amdgcn_global_load_lds(
        (const __attribute__((address_space(1))) void*)g,
        (__attribute__((address_space(3))) void*)lds, 16, 0, 0);
}

template <int MODE>
__global__ __launch_bounds__(256) void hgemm(
    const f16* __restrict__ A, const f16* __restrict__ Bt,
    const float* __restrict__ bias, f16* __restrict__ C, int K, int N) {
    __shared__ __align__(16) f16 As[2 * 128 * 64];   // 32 KB
    __shared__ __align__(16) f16 Bs[2 * 128 * 64];   // 32 KB
    const int tid = threadIdx.x;
    const int lane = tid & 63, w = tid >> 6;
    const int wm = w >> 1, wn = w & 1;

    // XCD-bijective swizzle (m204): contiguous chunks per XCD
    const int gx = gridDim.x;
    const int nwg = gx * gridDim.y;
    int lin = blockIdx.y * gx + blockIdx.x;
    {
        int q = nwg >> 3, r = nwg & 7;
        int xcd = lin & 7, j = lin >> 3;
        lin = (xcd < r ? xcd * (q + 1) : r * (q + 1) + (xcd - r) * q) + j;
    }
    const int bn = lin % gx, bm = lin / gx;

    f32x4 acc[4][4] = {};

    // Staging: thread t, chunk i (0..3) owns LDS bytes [t*16 + i*4096] of a
    // 16 KB buffer = row-major [128 rows][8 slots of 16B]:
    //   row = (t>>3) + i*32, linear slot = t&7.
    const int srow = tid >> 3;
    const int sslot = tid & 7;

    const int nt = K >> 6;                 // K/64 tiles

    // prologue: stage tile 0 into buffer 0
#pragma unroll
    for (int i = 0; i < 4; ++i) {
        int row = srow + i * 32;
        int g = sslot ^ (row & 7);
        gload_lds16(A + (size_t)(bm * 128 + row) * K + g * 8,
                    (char*)As + tid * 16 + i * 4096);
        gload_lds16(Bt + (size_t)(bn * 128 + row) * K + g * 8,
                    (char*)Bs + tid * 16 + i * 4096);
    }
    __syncthreads();

    int cur = 0;
    const int kg = lane >> 4;
    for (int t = 0; t < nt; ++t) {
        // stage next tile into the other buffer (overlaps with compute below)
        if (t + 1 < nt) {
            int k0 = (t + 1) << 6;
            int nb = (cur ^ 1) * 16384;
#pragma unroll
            for (int i = 0; i < 4; ++i) {
                int row = srow + i * 32;
                int g = sslot ^ (row & 7);
                gload_lds16(A + (size_t)(bm * 128 + row) * K + k0 + g * 8,
                            (char*)As + nb + tid * 16 + i * 4096);
                gload_lds16(Bt + (size_t)(bn * 128 + row) * K + k0 + g * 8,
                            (char*)Bs + nb + tid * 16 + i * 4096);
            }
        }
        // compute current buffer: 2 k-steps of 32
        int cb = cur * 16384;
#pragma unroll
        for (int kk = 0; kk < 2; ++kk) {
            f16x8 af[4], bf[4];
#pragma unroll
            for (int m = 0; m < 4; ++m) {
                int row = wm * 64 + m * 16 + (lane & 15);
                int s = (kk * 4 + kg) ^ (row & 7);
                af[m] = *reinterpret_cast<const f16x8*>((const char*)As + cb + row * 128 + s * 16);
            }
#pragma unroll
            for (int n = 0; n < 4; ++n) {
                int row = wn * 64 + n * 16 + (lane & 15);
                int s = (kk * 4 + kg) ^ (row & 7);
                bf[n] = *reinterpret_cast<const f16x8*>((const char*)Bs + cb + row * 128 + s * 16);
            }
#pragma unroll
            for (int m = 0; m < 4; ++m)
#pragma unroll
                for (int n = 0; n < 4; ++n)
                    acc[m][n] = __builtin_amdgcn_mfma_f32_16x16x32_f16(af[m], bf[n], acc[m][n], 0, 0, 0);
        }
        __syncthreads();       // drains vmcnt (next tile staged) + lgkm; guards buffer reuse
        cur ^= 1;
    }

    // epilogue: C row = (lane>>4)*4 + reg, col = lane&15 (m89-verified mapping)
#pragma unroll
    for (int n = 0; n < 4; ++n) {
        int colg = bn * 128 + wn * 64 + n * 16 + (lane & 15);
        float bv = (MODE == 1) ? bias[colg] : 0.f;
#pragma unroll
        for (int m = 0; m < 4; ++m) {
            int rbase = bm * 128 + wm * 64 + m * 16 + ((lane >> 4) << 2);
#pragma unroll
            for (int r = 0; r < 4; ++r) {
                float xv = acc[m][n][r];
                if (MODE == 1) { xv += bv; xv = fmaxf(xv, 0.f); }
                C[(size_t)(rbase + r) * N + colg] = (f16)xv;
            }
        }
    }
}

// ---------------------------------------------------------------------------
// Final: aggregate logits (D=32, stride 128) + bias + log_softmax, fused.
// 256-thread blocks, 8 nodes/block (2 per wave, 32 lanes each).
// ---------------------------------------------------------------------------
__global__ __launch_bounds__(256) void final_agg_softmax(
    const f16* __restrict__ in,     // [MPAD][128], cols 0..31 valid
    float* __restrict__ out,        // [NN][32]
    const int* __restrict__ rowptr, const int2* __restrict__ colw,
    const float* __restrict__ dinv, const float* __restrict__ b4) {
    int n = blockIdx.x * 8 + (threadIdx.x >> 5);
    int c = threadIdx.x & 31;
    if (n >= NN) return;
    float di = dinv[n];
    float acc = di * di * (float)in[(size_t)n * 128 + c];
    int e0 = rowptr[n], e1 = rowptr[n + 1];
#pragma unroll 4
    for (int e = e0; e < e1; ++e) {
        int2 cw = colw[e];
        acc = fmaf(di * __int_as_float(cw.y), (float)in[(size_t)cw.x * 128 + c], acc);
    }
    float v = acc + b4[c];
    float mx = v;
#pragma unroll
    for (int o = 16; o; o >>= 1) mx = fmaxf(mx, __shfl_xor(mx, o, 32));
    float e = expf(v - mx);
    float s = e;
#pragma unroll
    for (int o = 16; o; o >>= 1) s += __shfl_xor(s, o, 32);
    out[(size_t)n * 32 + c] = v - mx - logf(s);
}

// ---------------------------------------------------------------------------

extern "C" void kernel_launch(void* const* d_in, const int* in_sizes, int n_in,
                              void* d_out, int out_size, void* d_ws, size_t ws_size,
                              hipStream_t stream) {
    const float* x  = (const float*)d_in[0];
    const int* eidx = (const int*)d_in[1];
    const float* W1 = (const float*)d_in[2]; const float* b1 = (const float*)d_in[3];
    const float* W2 = (const float*)d_in[4]; const float* b2 = (const float*)d_in[5];
    const float* W3 = (const float*)d_in[6]; const float* b3 = (const float*)d_in[7];
    const float* W4 = (const float*)d_in[8]; const float* b4 = (const float*)d_in[9];
    float* out = (float*)d_out;

    // workspace carve-up (~47 MB)
    f16* P1    = (f16*)d_ws;                           // [MPAD][<=1024]
    f16* P2    = P1 + (size_t)MPAD * 1024;             // [MPAD][<=1024]
    f16* xh    = P2 + (size_t)MPAD * 1024;             // [NN][128]
    f16* Wt1   = xh + (size_t)NN * 128;                // [512][128]
    f16* Wt2   = Wt1 + 512 * 128;                      // [1024][512]
    f16* Wt3   = Wt2 + 1024 * 512;                     // [512][1024]
    f16* Wt4   = Wt3 + 512 * 1024;                     // [128][512] (zero-padded)
    int2* colw = (int2*)(Wt4 + 128 * 512);             // NE {src, dinv[src]}
    int* degi  = (int*)(colw + NE);                    // NN
    int* rowptr = degi + NN;                           // NN+1
    int* fill  = rowptr + (NN + 1);                    // NN
    float* dinv = (float*)(fill + NN);                 // NN

    const int B256 = 256;
    int gE = (NE + B256 - 1) / B256;
    int gN4 = (NN + 3) / 4;
    const int PREP_ELEMS = 512 * 128 + 1024 * 512 + 512 * 1024 + 128 * 512 + NN * D_IN + NN;

    // --- preprocessing (4 dispatches) ---
    prep_all<<<(PREP_ELEMS + B256 - 1) / B256, B256, 0, stream>>>(
        W1, W2, W3, W4, x, Wt1, Wt2, Wt3, Wt4, xh, degi);
    count_deg<<<gE, B256, 0, stream>>>(eidx, degi);
    scan_rowptr<<<1, 1024, 0, stream>>>(degi, rowptr, fill, dinv);
    scatter_edges<<<gE, B256, 0, stream>>>(eidx, dinv, fill, colw);

    // --- layer 1: aggregate xh (fp16, D=128), GEMM1 + bias + relu ---
    agg_kernel<2, 0><<<gN4, B256, 0, stream>>>(xh, P1, rowptr, colw, dinv, nullptr);
    hgemm<1><<<dim3(D_H1 / 128, MPAD / 128), B256, 0, stream>>>(P1, Wt1, b1, P2, D_IN, D_H1);

    // --- layer 2: aggregate h1 (D=512), GEMM2 + bias + relu ---
    agg_kernel<8, 0><<<gN4, B256, 0, stream>>>(P2, P1, rowptr, colw, dinv, nullptr);
    hgemm<1><<<dim3(D_H2 / 128, MPAD / 128), B256, 0, stream>>>(P1, Wt2, b2, P2, D_H1, D_H2);

    // --- layer 3: GEMM3 (plain), aggregate + bias + relu ---
    hgemm<0><<<dim3(D_H3 / 128, MPAD / 128), B256, 0, stream>>>(P2, Wt3, nullptr, P1, D_H2, D_H3);
    agg_kernel<8, 1><<<gN4, B256, 0, stream>>>(P1, P2, rowptr, colw, dinv, b3);

    // --- layer 4: MFMA GEMM on zero-padded W4 (N=128), fused agg+softmax ---
    hgemm<0><<<dim3(1, MPAD / 128), B256, 0, stream>>>(P2, Wt4, nullptr, P1, D_H3, 128);
    final_agg_softmax<<<(NN + 7) / 8, B256, 0, stream>>>(P1, out, rowptr, colw, dinv, b4);
}

// Round 15
// 235.297 us; speedup vs baseline: 1.0523x; 1.0523x over previous
//
#include <hip/hip_runtime.h>
#include <math.h>

typedef _Float16 f16;
typedef f16 f16x8 __attribute__((ext_vector_type(8)));
typedef f16 f16x2 __attribute__((ext_vector_type(2)));
typedef float f32x4 __attribute__((ext_vector_type(4)));

constexpr int NN = 10000;      // nodes
constexpr int NE = 160000;     // edges (before self-loops)
constexpr int MPAD = 10112;    // 79 * 128, row padding for 128-tiles
constexpr int D_IN = 128, D_H1 = 512, D_H2 = 1024, D_H3 = 512, D_OUT = 32;

// ---------------------------------------------------------------------------
// Kernel 1: all one-shot prep — zero degi, convert weights (transposed fp16,
// K-contiguous), convert x to fp16. No inter-dependencies.
// ---------------------------------------------------------------------------
__global__ void prep_all(const float* __restrict__ W1, const float* __restrict__ W2,
                         const float* __restrict__ W3, const float* __restrict__ W4,
                         const float* __restrict__ x,
                         f16* __restrict__ Wt1, f16* __restrict__ Wt2,
                         f16* __restrict__ Wt3, f16* __restrict__ Wt4,
                         f16* __restrict__ xh, int* __restrict__ degi) {
    int idx = blockIdx.x * blockDim.x + threadIdx.x;
    if (idx < 512 * 128) {               // Wt1 [512][128] <- W1 [128][512]
        int n = idx >> 7, k = idx & 127;
        Wt1[idx] = (f16)W1[k * 512 + n];
        return;
    }
    idx -= 512 * 128;
    if (idx < 1024 * 512) {              // Wt2 [1024][512] <- W2 [512][1024]
        int n = idx >> 9, k = idx & 511;
        Wt2[idx] = (f16)W2[k * 1024 + n];
        return;
    }
    idx -= 1024 * 512;
    if (idx < 512 * 1024) {              // Wt3 [512][1024] <- W3 [1024][512]
        int n = idx >> 10, k = idx & 1023;
        Wt3[idx] = (f16)W3[k * 512 + n];
        return;
    }
    idx -= 512 * 1024;
    if (idx < 128 * 512) {               // Wt4 [128][512] <- W4 [512][32], zero-padded
        int n = idx >> 9, k = idx & 511;
        Wt4[idx] = (n < 32) ? (f16)W4[k * 32 + n] : (f16)0.f;
        return;
    }
    idx -= 128 * 512;
    if (idx < NN * D_IN) {               // xh <- x (fp32 -> fp16)
        xh[idx] = (f16)x[idx];
        return;
    }
    idx -= NN * D_IN;
    if (idx < NN) degi[idx] = 0;
}

// Convert edge_index (int64 or int32 layout, detected per-wave) -> src/dst,
// and count in-degrees. int64 layout => odd 32-bit words all zero (ids<10000);
// for int32 layout P(64 consecutive odd words all zero) ~ (1e-4)^64 ~ 0.
__global__ void convert_count(const int* __restrict__ e,
                              int* __restrict__ srcA, int* __restrict__ dstA,
                              int* __restrict__ degi) {
    int i = blockIdx.x * blockDim.x + threadIdx.x;
    bool nz = (i < NE) && (e[2 * i + 1] != 0);
    bool is32 = __any(nz);               // wave-uniform layout verdict
    if (i >= NE) return;
    int s, d;
    if (is32) { s = e[i];     d = e[NE + i]; }
    else      { s = e[2 * i]; d = e[2 * NE + 2 * i]; }
    srcA[i] = s; dstA[i] = d;
    atomicAdd(&degi[d], 1);
}

// Single-block scan: int4-vectorized (4 elems/thread, 3 outer iters),
// degi -> rowptr (exclusive) + fill copy + dinv.
__global__ __launch_bounds__(1024) void scan_rowptr(
    const int* __restrict__ degi, int* __restrict__ rowptr,
    int* __restrict__ fill, float* __restrict__ dinv) {
    __shared__ int wsum[16];
    __shared__ int carry_s;
    int tid = threadIdx.x;
    int lane = tid & 63, wid = tid >> 6;
    if (tid == 0) carry_s = 0;
    for (int base = 0; base < NN; base += 4096) {
        int i4 = base + tid * 4;
        int4 v = {0, 0, 0, 0};
        if (i4 + 3 < NN) {
            v = *reinterpret_cast<const int4*>(degi + i4);
        } else {
            if (i4 + 0 < NN) v.x = degi[i4 + 0];
            if (i4 + 1 < NN) v.y = degi[i4 + 1];
            if (i4 + 2 < NN) v.z = degi[i4 + 2];
            if (i4 + 3 < NN) v.w = degi[i4 + 3];
        }
        if (i4 + 0 < NN) dinv[i4 + 0] = rsqrtf((float)(v.x + 1));  // +1 self-loop
        if (i4 + 1 < NN) dinv[i4 + 1] = rsqrtf((float)(v.y + 1));
        if (i4 + 2 < NN) dinv[i4 + 2] = rsqrtf((float)(v.z + 1));
        if (i4 + 3 < NN) dinv[i4 + 3] = rsqrtf((float)(v.w + 1));
        // serial inclusive scan of the 4 local elements
        int s1 = v.x, s2 = s1 + v.y, s3 = s2 + v.z, s4 = s3 + v.w;
        // wave inclusive scan of thread totals
        int xs = s4;
#pragma unroll
        for (int off = 1; off < 64; off <<= 1) {
            int t = __shfl_up(xs, off, 64);
            if (lane >= off) xs += t;
        }
        if (lane == 63) wsum[wid] = xs;
        __syncthreads();                       // B1 (also covers carry_s update)
        if (tid < 16) {
            int y = wsum[tid];
#pragma unroll
            for (int off = 1; off < 16; off <<= 1) {
                int t = __shfl_up(y, off, 16);
                if (tid >= off) y += t;
            }
            wsum[tid] = y;
        }
        __syncthreads();                       // B2
        int woff = wid ? wsum[wid - 1] : 0;
        int excl = (xs - s4) + woff + carry_s; // exclusive prefix of elem 0
        int4 r; r.x = excl; r.y = excl + s1; r.z = excl + s2; r.w = excl + s3;
        if (i4 + 3 < NN) {
            *reinterpret_cast<int4*>(rowptr + i4) = r;
            *reinterpret_cast<int4*>(fill + i4)   = r;
        } else {
            if (i4 + 0 < NN) { rowptr[i4 + 0] = r.x; fill[i4 + 0] = r.x; }
            if (i4 + 1 < NN) { rowptr[i4 + 1] = r.y; fill[i4 + 1] = r.y; }
            if (i4 + 2 < NN) { rowptr[i4 + 2] = r.z; fill[i4 + 2] = r.z; }
            if (i4 + 3 < NN) { rowptr[i4 + 3] = r.w; fill[i4 + 3] = r.w; }
        }
        __syncthreads();                       // B3: all carry_s reads done
        if (tid == 1023) carry_s = excl + s4;
    }
    if (tid == 1023) rowptr[NN] = carry_s;
}

__global__ void scatter_edges(const int* __restrict__ srcA, const int* __restrict__ dstA,
                              int* __restrict__ fill, int* __restrict__ col) {
    int i = blockIdx.x * blockDim.x + threadIdx.x;
    if (i >= NE) return;
    int p = atomicAdd(&fill[dstA[i]], 1);
    col[p] = srcA[i];
}

// ---------------------------------------------------------------------------
// Pull aggregation (fp16 in/out): 256-thread blocks, 4 nodes/block (1 wave ea).
// out[n,:] = dinv[n]^2*in[n,:] + sum_e dinv[n]*dinv[src]*in[src,:]
// MODE 0: plain   MODE 1: +bias, relu.  VEC in {2,8}, D = 64*VEC.
// Edge loop unrolled 4-deep for gather-latency pipelining.
// ---------------------------------------------------------------------------
template <int VEC>
__device__ __forceinline__ void acc_row(const f16* p, float w, float (&a)[VEC]) {
    if constexpr (VEC == 8) {
        f16x8 t = *reinterpret_cast<const f16x8*>(p);
#pragma unroll
        for (int j = 0; j < 8; ++j) a[j] = fmaf(w, (float)t[j], a[j]);
    } else {
        f16x2 t = *reinterpret_cast<const f16x2*>(p);
        a[0] = fmaf(w, (float)t[0], a[0]);
        a[1] = fmaf(w, (float)t[1], a[1]);
    }
}

template <int VEC, int MODE>
__global__ __launch_bounds__(256) void agg_kernel(
    const f16* __restrict__ in, f16* __restrict__ out,
    const int* __restrict__ rowptr, const int* __restrict__ col,
    const float* __restrict__ dinv, const float* __restrict__ bias) {
    const int D = 64 * VEC;
    int n = blockIdx.x * 4 + (threadIdx.x >> 6);
    if (n >= NN) return;
    int lane = threadIdx.x & 63;
    int d0 = lane * VEC;
    float di = dinv[n];
    float acc[VEC];
#pragma unroll
    for (int v = 0; v < VEC; ++v) acc[v] = 0.f;
    acc_row<VEC>(in + (size_t)n * D + d0, di * di, acc);
    int e0 = rowptr[n], e1 = rowptr[n + 1];
#pragma unroll 4
    for (int e = e0; e < e1; ++e) {
        int s = col[e];
        acc_row<VEC>(in + (size_t)s * D + d0, di * dinv[s], acc);
    }
    f16 o[VEC];
#pragma unroll
    for (int v = 0; v < VEC; ++v) {
        float xv = acc[v];
        if (MODE >= 1) xv += bias[d0 + v];
        if (MODE == 1) xv = fmaxf(xv, 0.f);
        o[v] = (f16)xv;
    }
    if constexpr (VEC == 8)
        *reinterpret_cast<f16x8*>(out + (size_t)n * D + d0) = *reinterpret_cast<f16x8*>(o);
    else
        *reinterpret_cast<f16x2*>(out + (size_t)n * D + d0) = *reinterpret_cast<f16x2*>(o);
}

// ---------------------------------------------------------------------------
// fp16 MFMA GEMM v2: C[M,N] = A[M,K] @ Bt[N,K]^T, fp32 accumulate, fp16 out.
// 128x128 tile, BK=64, double-buffered LDS, 2-phase prefetch pipeline
// (stage t+1 -> compute t -> one barrier/iter). 256 threads = 4 waves (2x2),
// 64x64/wave, mfma_f32_16x16x32_f16 4x4 frags, 2 k-steps per tile.
// M%128==0, N%128==0, K%64==0.
// LDS linear dest (global_load_lds); 16B-slot XOR swizzle (8 slots/row):
// source slot g = lin ^ (row&7), ds_read slot (kk*4+kg) ^ (row&7) — same
// involution both sides (rule 21); 2-way residual bank aliasing = free.
// XCD-bijective block swizzle (m204). MODE 0: plain  MODE 1: +bias, relu.
// ---------------------------------------------------------------------------
__device__ __forceinline__ void gload_lds16(const void* g, void* lds) {
    __builtin_amdgcn_global_load_lds(
        (const __attribute__((address_space(1))) void*)g,
        (__attribute__((address_space(3))) void*)lds, 16, 0, 0);
}

template <int MODE>
__global__ __launch_bounds__(256) void hgemm(
    const f16* __restrict__ A, const f16* __restrict__ Bt,
    const float* __restrict__ bias, f16* __restrict__ C, int K, int N) {
    __shared__ __align__(16) f16 As[2 * 128 * 64];   // 32 KB
    __shared__ __align__(16) f16 Bs[2 * 128 * 64];   // 32 KB
    const int tid = threadIdx.x;
    const int lane = tid & 63, w = tid >> 6;
    const int wm = w >> 1, wn = w & 1;

    // XCD-bijective swizzle (m204): contiguous chunks per XCD
    const int gx = gridDim.x;
    const int nwg = gx * gridDim.y;
    int lin = blockIdx.y * gx + blockIdx.x;
    {
        int q = nwg >> 3, r = nwg & 7;
        int xcd = lin & 7, j = lin >> 3;
        lin = (xcd < r ? xcd * (q + 1) : r * (q + 1) + (xcd - r) * q) + j;
    }
    const int bn = lin % gx, bm = lin / gx;

    f32x4 acc[4][4] = {};

    // Staging: thread t, chunk i (0..3) owns LDS bytes [t*16 + i*4096] of a
    // 16 KB buffer = row-major [128 rows][8 slots of 16B]:
    //   row = (t>>3) + i*32, linear slot = t&7.
    const int srow = tid >> 3;
    const int sslot = tid & 7;

    const int nt = K >> 6;                 // K/64 tiles

    // prologue: stage tile 0 into buffer 0
#pragma unroll
    for (int i = 0; i < 4; ++i) {
        int row = srow + i * 32;
        int g = sslot ^ (row & 7);
        gload_lds16(A + (size_t)(bm * 128 + row) * K + g * 8,
                    (char*)As + tid * 16 + i * 4096);
        gload_lds16(Bt + (size_t)(bn * 128 + row) * K + g * 8,
                    (char*)Bs + tid * 16 + i * 4096);
    }
    __syncthreads();

    int cur = 0;
    const int kg = lane >> 4;
    for (int t = 0; t < nt; ++t) {
        // stage next tile into the other buffer (overlaps with compute below)
        if (t + 1 < nt) {
            int k0 = (t + 1) << 6;
            int nb = (cur ^ 1) * 16384;
#pragma unroll
            for (int i = 0; i < 4; ++i) {
                int row = srow + i * 32;
                int g = sslot ^ (row & 7);
                gload_lds16(A + (size_t)(bm * 128 + row) * K + k0 + g * 8,
                            (char*)As + nb + tid * 16 + i * 4096);
                gload_lds16(Bt + (size_t)(bn * 128 + row) * K + k0 + g * 8,
                            (char*)Bs + nb + tid * 16 + i * 4096);
            }
        }
        // compute current buffer: 2 k-steps of 32
        int cb = cur * 16384;
#pragma unroll
        for (int kk = 0; kk < 2; ++kk) {
            f16x8 af[4], bf[4];
#pragma unroll
            for (int m = 0; m < 4; ++m) {
                int row = wm * 64 + m * 16 + (lane & 15);
                int s = (kk * 4 + kg) ^ (row & 7);
                af[m] = *reinterpret_cast<const f16x8*>((const char*)As + cb + row * 128 + s * 16);
            }
#pragma unroll
            for (int n = 0; n < 4; ++n) {
                int row = wn * 64 + n * 16 + (lane & 15);
                int s = (kk * 4 + kg) ^ (row & 7);
                bf[n] = *reinterpret_cast<const f16x8*>((const char*)Bs + cb + row * 128 + s * 16);
            }
#pragma unroll
            for (int m = 0; m < 4; ++m)
#pragma unroll
                for (int n = 0; n < 4; ++n)
                    acc[m][n] = __builtin_amdgcn_mfma_f32_16x16x32_f16(af[m], bf[n], acc[m][n], 0, 0, 0);
        }
        __syncthreads();       // drains vmcnt (next tile staged) + lgkm; guards buffer reuse
        cur ^= 1;
    }

    // epilogue: C row = (lane>>4)*4 + reg, col = lane&15 (m89-verified mapping)
#pragma unroll
    for (int n = 0; n < 4; ++n) {
        int colg = bn * 128 + wn * 64 + n * 16 + (lane & 15);
        float bv = (MODE == 1) ? bias[colg] : 0.f;
#pragma unroll
        for (int m = 0; m < 4; ++m) {
            int rbase = bm * 128 + wm * 64 + m * 16 + ((lane >> 4) << 2);
#pragma unroll
            for (int r = 0; r < 4; ++r) {
                float xv = acc[m][n][r];
                if (MODE == 1) { xv += bv; xv = fmaxf(xv, 0.f); }
                C[(size_t)(rbase + r) * N + colg] = (f16)xv;
            }
        }
    }
}

// ---------------------------------------------------------------------------
// Final: aggregate logits (D=32, stride 128) + bias + log_softmax, fused.
// 256-thread blocks, 8 nodes/block (2 per wave, 32 lanes each).
// ---------------------------------------------------------------------------
__global__ __launch_bounds__(256) void final_agg_softmax(
    const f16* __restrict__ in,     // [MPAD][128], cols 0..31 valid
    float* __restrict__ out,        // [NN][32]
    const int* __restrict__ rowptr, const int* __restrict__ col,
    const float* __restrict__ dinv, const float* __restrict__ b4) {
    int n = blockIdx.x * 8 + (threadIdx.x >> 5);
    int c = threadIdx.x & 31;
    if (n >= NN) return;
    float di = dinv[n];
    float acc = di * di * (float)in[(size_t)n * 128 + c];
    int e0 = rowptr[n], e1 = rowptr[n + 1];
#pragma unroll 4
    for (int e = e0; e < e1; ++e) {
        int s = col[e];
        acc = fmaf(di * dinv[s], (float)in[(size_t)s * 128 + c], acc);
    }
    float v = acc + b4[c];
    float mx = v;
#pragma unroll
    for (int o = 16; o; o >>= 1) mx = fmaxf(mx, __shfl_xor(mx, o, 32));
    float e = expf(v - mx);
    float s = e;
#pragma unroll
    for (int o = 16; o; o >>= 1) s += __shfl_xor(s, o, 32);
    out[(size_t)n * 32 + c] = v - mx - logf(s);
}

// ---------------------------------------------------------------------------

extern "C" void kernel_launch(void* const* d_in, const int* in_sizes, int n_in,
                              void* d_out, int out_size, void* d_ws, size_t ws_size,
                              hipStream_t stream) {
    const float* x  = (const float*)d_in[0];
    const int* eidx = (const int*)d_in[1];
    const float* W1 = (const float*)d_in[2]; const float* b1 = (const float*)d_in[3];
    const float* W2 = (const float*)d_in[4]; const float* b2 = (const float*)d_in[5];
    const float* W3 = (const float*)d_in[6]; const float* b3 = (const float*)d_in[7];
    const float* W4 = (const float*)d_in[8]; const float* b4 = (const float*)d_in[9];
    float* out = (float*)d_out;

    // workspace carve-up (~49 MB)
    f16* P1    = (f16*)d_ws;                           // [MPAD][<=1024]
    f16* P2    = P1 + (size_t)MPAD * 1024;             // [MPAD][<=1024]
    f16* xh    = P2 + (size_t)MPAD * 1024;             // [NN][128]
    f16* Wt1   = xh + (size_t)NN * 128;                // [512][128]
    f16* Wt2   = Wt1 + 512 * 128;                      // [1024][512]
    f16* Wt3   = Wt2 + 1024 * 512;                     // [512][1024]
    f16* Wt4   = Wt3 + 512 * 1024;                     // [128][512] (zero-padded)
    int* srcA  = (int*)(Wt4 + 128 * 512);              // NE
    int* dstA  = srcA + NE;
    int* colA  = dstA + NE;
    int* degi  = colA + NE;                            // NN
    int* rowptr = degi + NN;                           // NN+1
    int* fill  = rowptr + (NN + 1);                    // NN
    float* dinv = (float*)(fill + NN);                 // NN

    const int B256 = 256;
    int gE = (NE + B256 - 1) / B256;
    int gN4 = (NN + 3) / 4;
    const int PREP_ELEMS = 512 * 128 + 1024 * 512 + 512 * 1024 + 128 * 512 + NN * D_IN + NN;

    // --- preprocessing (4 dispatches) ---
    prep_all<<<(PREP_ELEMS + B256 - 1) / B256, B256, 0, stream>>>(
        W1, W2, W3, W4, x, Wt1, Wt2, Wt3, Wt4, xh, degi);
    convert_count<<<gE, B256, 0, stream>>>(eidx, srcA, dstA, degi);
    scan_rowptr<<<1, 1024, 0, stream>>>(degi, rowptr, fill, dinv);
    scatter_edges<<<gE, B256, 0, stream>>>(srcA, dstA, fill, colA);

    // --- layer 1: aggregate xh (fp16, D=128), GEMM1 + bias + relu ---
    agg_kernel<2, 0><<<gN4, B256, 0, stream>>>(xh, P1, rowptr, colA, dinv, nullptr);
    hgemm<1><<<dim3(D_H1 / 128, MPAD / 128), B256, 0, stream>>>(P1, Wt1, b1, P2, D_IN, D_H1);

    // --- layer 2: aggregate h1 (D=512), GEMM2 + bias + relu ---
    agg_kernel<8, 0><<<gN4, B256, 0, stream>>>(P2, P1, rowptr, colA, dinv, nullptr);
    hgemm<1><<<dim3(D_H2 / 128, MPAD / 128), B256, 0, stream>>>(P1, Wt2, b2, P2, D_H1, D_H2);

    // --- layer 3: GEMM3 (plain), aggregate + bias + relu ---
    hgemm<0><<<dim3(D_H3 / 128, MPAD / 128), B256, 0, stream>>>(P2, Wt3, nullptr, P1, D_H2, D_H3);
    agg_kernel<8, 1><<<gN4, B256, 0, stream>>>(P1, P2, rowptr, colA, dinv, b3);

    // --- layer 4: MFMA GEMM on zero-padded W4 (N=128), fused agg+softmax ---
    hgemm<0><<<dim3(1, MPAD / 128), B256, 0, stream>>>(P2, Wt4, nullptr, P1, D_H3, 128);
    final_agg_softmax<<<(NN + 7) / 8, B256, 0, stream>>>(P1, out, rowptr, colA, dinv, b4);
}

// Round 16
// 225.754 us; speedup vs baseline: 1.0967x; 1.0423x over previous
//
#include <hip/hip_runtime.h>
#include <math.h>

typedef _Float16 f16;
typedef f16 f16x8 __attribute__((ext_vector_type(8)));
typedef f16 f16x2 __attribute__((ext_vector_type(2)));
typedef float f32x4 __attribute__((ext_vector_type(4)));

constexpr int NN = 10000;      // nodes
constexpr int NE = 160000;     // edges (before self-loops)
constexpr int MPAD = 10112;    // 79 * 128, row padding for 128-tiles
constexpr int D_IN = 128, D_H1 = 512, D_H2 = 1024, D_H3 = 512, D_OUT = 32;

// ---------------------------------------------------------------------------
// Kernel 1: all one-shot prep — zero degi, convert weights (transposed fp16,
// K-contiguous), convert x to fp16. No inter-dependencies.
// Wt4 is N-padded to 64 rows (zeros beyond 32).
// ---------------------------------------------------------------------------
__global__ void prep_all(const float* __restrict__ W1, const float* __restrict__ W2,
                         const float* __restrict__ W3, const float* __restrict__ W4,
                         const float* __restrict__ x,
                         f16* __restrict__ Wt1, f16* __restrict__ Wt2,
                         f16* __restrict__ Wt3, f16* __restrict__ Wt4,
                         f16* __restrict__ xh, int* __restrict__ degi) {
    int idx = blockIdx.x * blockDim.x + threadIdx.x;
    if (idx < 512 * 128) {               // Wt1 [512][128] <- W1 [128][512]
        int n = idx >> 7, k = idx & 127;
        Wt1[idx] = (f16)W1[k * 512 + n];
        return;
    }
    idx -= 512 * 128;
    if (idx < 1024 * 512) {              // Wt2 [1024][512] <- W2 [512][1024]
        int n = idx >> 9, k = idx & 511;
        Wt2[idx] = (f16)W2[k * 1024 + n];
        return;
    }
    idx -= 1024 * 512;
    if (idx < 512 * 1024) {              // Wt3 [512][1024] <- W3 [1024][512]
        int n = idx >> 10, k = idx & 1023;
        Wt3[idx] = (f16)W3[k * 512 + n];
        return;
    }
    idx -= 512 * 1024;
    if (idx < 64 * 512) {                // Wt4 [64][512] <- W4 [512][32], zero-padded
        int n = idx >> 9, k = idx & 511;
        Wt4[idx] = (n < 32) ? (f16)W4[k * 32 + n] : (f16)0.f;
        return;
    }
    idx -= 64 * 512;
    if (idx < NN * D_IN) {               // xh <- x (fp32 -> fp16)
        xh[idx] = (f16)x[idx];
        return;
    }
    idx -= NN * D_IN;
    if (idx < NN) degi[idx] = 0;
}

// Convert edge_index (int64 or int32 layout, detected per-wave) -> src/dst,
// and count in-degrees. int64 layout => odd 32-bit words all zero (ids<10000);
// for int32 layout P(64 consecutive odd words all zero) ~ (1e-4)^64 ~ 0.
__global__ void convert_count(const int* __restrict__ e,
                              int* __restrict__ srcA, int* __restrict__ dstA,
                              int* __restrict__ degi) {
    int i = blockIdx.x * blockDim.x + threadIdx.x;
    bool nz = (i < NE) && (e[2 * i + 1] != 0);
    bool is32 = __any(nz);               // wave-uniform layout verdict
    if (i >= NE) return;
    int s, d;
    if (is32) { s = e[i];     d = e[NE + i]; }
    else      { s = e[2 * i]; d = e[2 * NE + 2 * i]; }
    srcA[i] = s; dstA[i] = d;
    atomicAdd(&degi[d], 1);
}

// Single-block scan: int4-vectorized (4 elems/thread, 3 outer iters),
// degi -> rowptr (exclusive) + fill copy + dinv.
__global__ __launch_bounds__(1024) void scan_rowptr(
    const int* __restrict__ degi, int* __restrict__ rowptr,
    int* __restrict__ fill, float* __restrict__ dinv) {
    __shared__ int wsum[16];
    __shared__ int carry_s;
    int tid = threadIdx.x;
    int lane = tid & 63, wid = tid >> 6;
    if (tid == 0) carry_s = 0;
    for (int base = 0; base < NN; base += 4096) {
        int i4 = base + tid * 4;
        int4 v = {0, 0, 0, 0};
        if (i4 + 3 < NN) {
            v = *reinterpret_cast<const int4*>(degi + i4);
        } else {
            if (i4 + 0 < NN) v.x = degi[i4 + 0];
            if (i4 + 1 < NN) v.y = degi[i4 + 1];
            if (i4 + 2 < NN) v.z = degi[i4 + 2];
            if (i4 + 3 < NN) v.w = degi[i4 + 3];
        }
        if (i4 + 0 < NN) dinv[i4 + 0] = rsqrtf((float)(v.x + 1));  // +1 self-loop
        if (i4 + 1 < NN) dinv[i4 + 1] = rsqrtf((float)(v.y + 1));
        if (i4 + 2 < NN) dinv[i4 + 2] = rsqrtf((float)(v.z + 1));
        if (i4 + 3 < NN) dinv[i4 + 3] = rsqrtf((float)(v.w + 1));
        // serial inclusive scan of the 4 local elements
        int s1 = v.x, s2 = s1 + v.y, s3 = s2 + v.z, s4 = s3 + v.w;
        // wave inclusive scan of thread totals
        int xs = s4;
#pragma unroll
        for (int off = 1; off < 64; off <<= 1) {
            int t = __shfl_up(xs, off, 64);
            if (lane >= off) xs += t;
        }
        if (lane == 63) wsum[wid] = xs;
        __syncthreads();                       // B1 (also covers carry_s update)
        if (tid < 16) {
            int y = wsum[tid];
#pragma unroll
            for (int off = 1; off < 16; off <<= 1) {
                int t = __shfl_up(y, off, 16);
                if (tid >= off) y += t;
            }
            wsum[tid] = y;
        }
        __syncthreads();                       // B2
        int woff = wid ? wsum[wid - 1] : 0;
        int excl = (xs - s4) + woff + carry_s; // exclusive prefix of elem 0
        int4 r; r.x = excl; r.y = excl + s1; r.z = excl + s2; r.w = excl + s3;
        if (i4 + 3 < NN) {
            *reinterpret_cast<int4*>(rowptr + i4) = r;
            *reinterpret_cast<int4*>(fill + i4)   = r;
        } else {
            if (i4 + 0 < NN) { rowptr[i4 + 0] = r.x; fill[i4 + 0] = r.x; }
            if (i4 + 1 < NN) { rowptr[i4 + 1] = r.y; fill[i4 + 1] = r.y; }
            if (i4 + 2 < NN) { rowptr[i4 + 2] = r.z; fill[i4 + 2] = r.z; }
            if (i4 + 3 < NN) { rowptr[i4 + 3] = r.w; fill[i4 + 3] = r.w; }
        }
        __syncthreads();                       // B3: all carry_s reads done
        if (tid == 1023) carry_s = excl + s4;
    }
    if (tid == 1023) rowptr[NN] = carry_s;
}

__global__ void scatter_edges(const int* __restrict__ srcA, const int* __restrict__ dstA,
                              int* __restrict__ fill, int* __restrict__ col) {
    int i = blockIdx.x * blockDim.x + threadIdx.x;
    if (i >= NE) return;
    int p = atomicAdd(&fill[dstA[i]], 1);
    col[p] = srcA[i];
}

// ---------------------------------------------------------------------------
// Pull aggregation (fp16 in/out): 256-thread blocks, 4 nodes/block (1 wave ea).
// out[n,:] = dinv[n]^2*in[n,:] + sum_e dinv[n]*dinv[src]*in[src,:]
// MODE 0: plain   MODE 1: +bias, relu.  VEC in {2,8}, D = 64*VEC.
// Edge loop unrolled 4-deep for gather-latency pipelining.
// ---------------------------------------------------------------------------
template <int VEC>
__device__ __forceinline__ void acc_row(const f16* p, float w, float (&a)[VEC]) {
    if constexpr (VEC == 8) {
        f16x8 t = *reinterpret_cast<const f16x8*>(p);
#pragma unroll
        for (int j = 0; j < 8; ++j) a[j] = fmaf(w, (float)t[j], a[j]);
    } else {
        f16x2 t = *reinterpret_cast<const f16x2*>(p);
        a[0] = fmaf(w, (float)t[0], a[0]);
        a[1] = fmaf(w, (float)t[1], a[1]);
    }
}

template <int VEC, int MODE>
__global__ __launch_bounds__(256) void agg_kernel(
    const f16* __restrict__ in, f16* __restrict__ out,
    const int* __restrict__ rowptr, const int* __restrict__ col,
    const float* __restrict__ dinv, const float* __restrict__ bias) {
    const int D = 64 * VEC;
    int n = blockIdx.x * 4 + (threadIdx.x >> 6);
    if (n >= NN) return;
    int lane = threadIdx.x & 63;
    int d0 = lane * VEC;
    float di = dinv[n];
    float acc[VEC];
#pragma unroll
    for (int v = 0; v < VEC; ++v) acc[v] = 0.f;
    acc_row<VEC>(in + (size_t)n * D + d0, di * di, acc);
    int e0 = rowptr[n], e1 = rowptr[n + 1];
#pragma unroll 4
    for (int e = e0; e < e1; ++e) {
        int s = col[e];
        acc_row<VEC>(in + (size_t)s * D + d0, di * dinv[s], acc);
    }
    f16 o[VEC];
#pragma unroll
    for (int v = 0; v < VEC; ++v) {
        float xv = acc[v];
        if (MODE >= 1) xv += bias[d0 + v];
        if (MODE == 1) xv = fmaxf(xv, 0.f);
        o[v] = (f16)xv;
    }
    if constexpr (VEC == 8)
        *reinterpret_cast<f16x8*>(out + (size_t)n * D + d0) = *reinterpret_cast<f16x8*>(o);
    else
        *reinterpret_cast<f16x2*>(out + (size_t)n * D + d0) = *reinterpret_cast<f16x2*>(o);
}

// ---------------------------------------------------------------------------
// fp16 MFMA GEMM v3: C[M,N] = A[M,K] @ Bt[N,K]^T, fp32 accumulate, fp16 out.
// 128xBN tile (BN in {64,128}), BK=64, double-buffered LDS, 2-phase prefetch
// (stage t+1 -> compute t -> one barrier/iter). 256 threads = 4 waves (2x2),
// 64x(BN/2) per wave, mfma_f32_16x16x32_f16 4x(BN/32) frags, 2 k-steps/tile.
// BN=64: LDS 48 KB -> 3 blocks/CU (24 waves) vs 2 at BN=128.
// M%128==0, N%BN==0, K%64==0.
// LDS linear dest (global_load_lds); 16B-slot XOR swizzle (8 slots/row):
// source slot g = lin ^ (row&7), ds_read slot (kk*4+kg) ^ (row&7) — same
// involution both sides (rule 21); 2-way residual bank aliasing = free.
// XCD-bijective block swizzle (m204). MODE 0: plain  MODE 1: +bias, relu.
// ---------------------------------------------------------------------------
__device__ __forceinline__ void gload_lds16(const void* g, void* lds) {
    __builtin_amdgcn_global_load_lds(
        (const __attribute__((address_space(1))) void*)g,
        (__attribute__((address_space(3))) void*)lds, 16, 0, 0);
}

template <int MODE, int BN>
__global__ __launch_bounds__(256) void hgemm(
    const f16* __restrict__ A, const f16* __restrict__ Bt,
    const float* __restrict__ bias, f16* __restrict__ C, int K, int N) {
    constexpr int BNC = BN / 32;            // B staging chunks (32 rows each)
    constexpr int NW = BN / 32;             // n-frags per wave (BN/2 cols / 16)
    constexpr int ABUF = 128 * 128;         // bytes per A buffer = 16 KB
    constexpr int BBUF = BN * 128;          // bytes per B buffer
    __shared__ __align__(16) f16 As[2 * 128 * 64];
    __shared__ __align__(16) f16 Bs[2 * BN * 64];
    const int tid = threadIdx.x;
    const int lane = tid & 63, w = tid >> 6;
    const int wm = w >> 1, wn = w & 1;

    // XCD-bijective swizzle (m204): contiguous chunks per XCD
    const int gx = gridDim.x;
    const int nwg = gx * gridDim.y;
    int lin = blockIdx.y * gx + blockIdx.x;
    {
        int q = nwg >> 3, r = nwg & 7;
        int xcd = lin & 7, j = lin >> 3;
        lin = (xcd < r ? xcd * (q + 1) : r * (q + 1) + (xcd - r) * q) + j;
    }
    const int bn = lin % gx, bm = lin / gx;

    f32x4 acc[4][NW] = {};

    // Staging: thread t, chunk i owns LDS bytes [t*16 + i*4096] of a buffer =
    // row-major [rows][8 slots of 16B]: row = (t>>3) + i*32, linear slot t&7.
    const int srow = tid >> 3;
    const int sslot = tid & 7;

    const int nt = K >> 6;                 // K/64 tiles

    // prologue: stage tile 0 into buffer 0
#pragma unroll
    for (int i = 0; i < 4; ++i) {
        int row = srow + i * 32;
        int g = sslot ^ (row & 7);
        gload_lds16(A + (size_t)(bm * 128 + row) * K + g * 8,
                    (char*)As + tid * 16 + i * 4096);
        if (i < BNC)
            gload_lds16(Bt + (size_t)(bn * BN + row) * K + g * 8,
                        (char*)Bs + tid * 16 + i * 4096);
    }
    __syncthreads();

    int cur = 0;
    const int kg = lane >> 4;
    for (int t = 0; t < nt; ++t) {
        // stage next tile into the other buffer (overlaps with compute below)
        if (t + 1 < nt) {
            int k0 = (t + 1) << 6;
            int nbA = (cur ^ 1) * ABUF;
            int nbB = (cur ^ 1) * BBUF;
#pragma unroll
            for (int i = 0; i < 4; ++i) {
                int row = srow + i * 32;
                int g = sslot ^ (row & 7);
                gload_lds16(A + (size_t)(bm * 128 + row) * K + k0 + g * 8,
                            (char*)As + nbA + tid * 16 + i * 4096);
                if (i < BNC)
                    gload_lds16(Bt + (size_t)(bn * BN + row) * K + k0 + g * 8,
                                (char*)Bs + nbB + tid * 16 + i * 4096);
            }
        }
        // compute current buffer: 2 k-steps of 32
        int cbA = cur * ABUF;
        int cbB = cur * BBUF;
#pragma unroll
        for (int kk = 0; kk < 2; ++kk) {
            f16x8 af[4], bf[NW];
#pragma unroll
            for (int m = 0; m < 4; ++m) {
                int row = wm * 64 + m * 16 + (lane & 15);
                int s = (kk * 4 + kg) ^ (row & 7);
                af[m] = *reinterpret_cast<const f16x8*>((const char*)As + cbA + row * 128 + s * 16);
            }
#pragma unroll
            for (int n = 0; n < NW; ++n) {
                int row = wn * (BN / 2) + n * 16 + (lane & 15);
                int s = (kk * 4 + kg) ^ (row & 7);
                bf[n] = *reinterpret_cast<const f16x8*>((const char*)Bs + cbB + row * 128 + s * 16);
            }
#pragma unroll
            for (int m = 0; m < 4; ++m)
#pragma unroll
                for (int n = 0; n < NW; ++n)
                    acc[m][n] = __builtin_amdgcn_mfma_f32_16x16x32_f16(af[m], bf[n], acc[m][n], 0, 0, 0);
        }
        __syncthreads();       // drains vmcnt (next tile staged) + lgkm; guards buffer reuse
        cur ^= 1;
    }

    // epilogue: C row = (lane>>4)*4 + reg, col = lane&15 (m89-verified mapping)
#pragma unroll
    for (int n = 0; n < NW; ++n) {
        int colg = bn * BN + wn * (BN / 2) + n * 16 + (lane & 15);
        float bv = (MODE == 1) ? bias[colg] : 0.f;
#pragma unroll
        for (int m = 0; m < 4; ++m) {
            int rbase = bm * 128 + wm * 64 + m * 16 + ((lane >> 4) << 2);
#pragma unroll
            for (int r = 0; r < 4; ++r) {
                float xv = acc[m][n][r];
                if (MODE == 1) { xv += bv; xv = fmaxf(xv, 0.f); }
                C[(size_t)(rbase + r) * N + colg] = (f16)xv;
            }
        }
    }
}

// ---------------------------------------------------------------------------
// Final: aggregate logits (D=32, stride 64) + bias + log_softmax, fused.
// 256-thread blocks, 8 nodes/block (2 per wave, 32 lanes each).
// ---------------------------------------------------------------------------
__global__ __launch_bounds__(256) void final_agg_softmax(
    const f16* __restrict__ in,     // [MPAD][64], cols 0..31 valid
    float* __restrict__ out,        // [NN][32]
    const int* __restrict__ rowptr, const int* __restrict__ col,
    const float* __restrict__ dinv, const float* __restrict__ b4) {
    int n = blockIdx.x * 8 + (threadIdx.x >> 5);
    int c = threadIdx.x & 31;
    if (n >= NN) return;
    float di = dinv[n];
    float acc = di * di * (float)in[(size_t)n * 64 + c];
    int e0 = rowptr[n], e1 = rowptr[n + 1];
#pragma unroll 4
    for (int e = e0; e < e1; ++e) {
        int s = col[e];
        acc = fmaf(di * dinv[s], (float)in[(size_t)s * 64 + c], acc);
    }
    float v = acc + b4[c];
    float mx = v;
#pragma unroll
    for (int o = 16; o; o >>= 1) mx = fmaxf(mx, __shfl_xor(mx, o, 32));
    float e = expf(v - mx);
    float s = e;
#pragma unroll
    for (int o = 16; o; o >>= 1) s += __shfl_xor(s, o, 32);
    out[(size_t)n * 32 + c] = v - mx - logf(s);
}

// ---------------------------------------------------------------------------

extern "C" void kernel_launch(void* const* d_in, const int* in_sizes, int n_in,
                              void* d_out, int out_size, void* d_ws, size_t ws_size,
                              hipStream_t stream) {
    const float* x  = (const float*)d_in[0];
    const int* eidx = (const int*)d_in[1];
    const float* W1 = (const float*)d_in[2]; const float* b1 = (const float*)d_in[3];
    const float* W2 = (const float*)d_in[4]; const float* b2 = (const float*)d_in[5];
    const float* W3 = (const float*)d_in[6]; const float* b3 = (const float*)d_in[7];
    const float* W4 = (const float*)d_in[8]; const float* b4 = (const float*)d_in[9];
    float* out = (float*)d_out;

    // workspace carve-up (~49 MB)
    f16* P1    = (f16*)d_ws;                           // [MPAD][<=1024]
    f16* P2    = P1 + (size_t)MPAD * 1024;             // [MPAD][<=1024]
    f16* xh    = P2 + (size_t)MPAD * 1024;             // [NN][128]
    f16* Wt1   = xh + (size_t)NN * 128;                // [512][128]
    f16* Wt2   = Wt1 + 512 * 128;                      // [1024][512]
    f16* Wt3   = Wt2 + 1024 * 512;                     // [512][1024]
    f16* Wt4   = Wt3 + 512 * 1024;                     // [64][512] (zero-padded)
    int* srcA  = (int*)(Wt4 + 64 * 512);               // NE
    int* dstA  = srcA + NE;
    int* colA  = dstA + NE;
    int* degi  = colA + NE;                            // NN
    int* rowptr = degi + NN;                           // NN+1
    int* fill  = rowptr + (NN + 1);                    // NN
    float* dinv = (float*)(fill + NN);                 // NN

    const int B256 = 256;
    int gE = (NE + B256 - 1) / B256;
    int gN4 = (NN + 3) / 4;
    const int PREP_ELEMS = 512 * 128 + 1024 * 512 + 512 * 1024 + 64 * 512 + NN * D_IN + NN;

    // --- preprocessing (4 dispatches) ---
    prep_all<<<(PREP_ELEMS + B256 - 1) / B256, B256, 0, stream>>>(
        W1, W2, W3, W4, x, Wt1, Wt2, Wt3, Wt4, xh, degi);
    convert_count<<<gE, B256, 0, stream>>>(eidx, srcA, dstA, degi);
    scan_rowptr<<<1, 1024, 0, stream>>>(degi, rowptr, fill, dinv);
    scatter_edges<<<gE, B256, 0, stream>>>(srcA, dstA, fill, colA);

    // --- layer 1: aggregate xh (fp16, D=128), GEMM1 + bias + relu ---
    agg_kernel<2, 0><<<gN4, B256, 0, stream>>>(xh, P1, rowptr, colA, dinv, nullptr);
    hgemm<1, 64><<<dim3(D_H1 / 64, MPAD / 128), B256, 0, stream>>>(P1, Wt1, b1, P2, D_IN, D_H1);

    // --- layer 2: aggregate h1 (D=512), GEMM2 + bias + relu ---
    agg_kernel<8, 0><<<gN4, B256, 0, stream>>>(P2, P1, rowptr, colA, dinv, nullptr);
    hgemm<1, 64><<<dim3(D_H2 / 64, MPAD / 128), B256, 0, stream>>>(P1, Wt2, b2, P2, D_H1, D_H2);

    // --- layer 3: GEMM3 (plain), aggregate + bias + relu ---
    hgemm<0, 64><<<dim3(D_H3 / 64, MPAD / 128), B256, 0, stream>>>(P2, Wt3, nullptr, P1, D_H2, D_H3);
    agg_kernel<8, 1><<<gN4, B256, 0, stream>>>(P1, P2, rowptr, colA, dinv, b3);

    // --- layer 4: MFMA GEMM on zero-padded W4 (N=64), fused agg+softmax ---
    hgemm<0, 64><<<dim3(1, MPAD / 128), B256, 0, stream>>>(P2, Wt4, nullptr, P1, D_H3, 64);
    final_agg_softmax<<<(NN + 7) / 8, B256, 0, stream>>>(P1, out, rowptr, colA, dinv, b4);
}